// Round 15
// baseline (224.441 us; speedup 1.0000x reference)
//
#include <hip/hip_runtime.h>
#include <stdint.h>

typedef uint16_t u16;
typedef float f32x4 __attribute__((ext_vector_type(4)));
typedef short bf16x8 __attribute__((ext_vector_type(8)));

constexpr int NB = 2, NS = 2048, ND = 2048, NH = 16, NKVH = 4, HDIM = 128;
constexpr int QKVD = 3072;
constexpr int TOK = NB * NS;
constexpr float SM_SCALE = 0.08838834764831845f; // 1/sqrt(128)
constexpr float LOG2E = 1.4426950408889634f;
constexpr float QK_SCALE = SM_SCALE * LOG2E;     // folded into K at rope time

#define WAITVM(N) asm volatile("s_waitcnt vmcnt(" #N ")" ::: "memory")
#define MEMFENCE asm volatile("" ::: "memory")

__device__ __forceinline__ u16 f2bf(float f) {
  union { float f; uint32_t u; } v; v.f = f;
  return (u16)((v.u + 0x7fffu + ((v.u >> 16) & 1u)) >> 16);
}
__device__ __forceinline__ uint32_t cvt_pk_bf16(float lo, float hi) {
  uint32_t r;
  asm("v_cvt_pk_bf16_f32 %0, %1, %2" : "=v"(r) : "v"(lo), "v"(hi));
  return r;
}

__device__ __forceinline__ void gload_lds16(const void* g, void* l) {
  void* gv = const_cast<void*>(g);
  __builtin_amdgcn_global_load_lds(
      (__attribute__((address_space(1))) void*)gv,
      (__attribute__((address_space(3))) void*)l, 16, 0, 0);
}

// ---------------- merged f32 -> bf16 conversion (3 tensors, 1 launch) ------
__global__ __launch_bounds__(256)
void cvt3(const float* __restrict__ x, const float* __restrict__ wq,
          const float* __restrict__ wo, u16* __restrict__ xb,
          u16* __restrict__ wqb, u16* __restrict__ wob) {
  constexpr int N1 = TOK * ND / 4, N2 = QKVD * ND / 4, N3 = ND * ND / 4;
  int i = blockIdx.x * 256 + threadIdx.x;
  const float* src; u16* dst; int j;
  if (i < N1)              { src = x;  dst = xb;  j = i; }
  else if (i < N1 + N2)    { src = wq; dst = wqb; j = i - N1; }
  else if (i < N1 + N2 + N3){ src = wo; dst = wob; j = i - N1 - N2; }
  else return;
  const float4 v = reinterpret_cast<const float4*>(src)[j];
  union { u16 h[4]; uint2 u; } o;
  o.h[0] = f2bf(v.x); o.h[1] = f2bf(v.y); o.h[2] = f2bf(v.z); o.h[3] = f2bf(v.w);
  reinterpret_cast<uint2*>(dst)[j] = o.u;
}

// ---------------- GEMM: C[M][N] = A[M][K] * B[N][K]^T (bf16 in) ------------
// Quad-buffered BK=32, prefetch distance 2: STAGE(kt+2) writes buf (kt+2)&3
// whose readers (round kt-2) finished before barrier kt-1 — one barrier per
// round, and every load gets ~2 rounds (~4000 cyc) to land, covering HBM
// misses. Gate vmcnt(8) = {kt+1,kt+2} in flight. MODE 0: f32 out.
// MODE 2: fused RoPE/split epilogue.
template <int MODE>
__global__ __launch_bounds__(256, 2)
void gemm_bt(const u16* __restrict__ A, const u16* __restrict__ Bm,
             void* __restrict__ Cv, int M, int N, int K,
             const float* __restrict__ fc, u16* __restrict__ Qb,
             u16* __restrict__ Kb, u16* __restrict__ Vt) {
  __shared__ u16 As[4][128 * 32];
  __shared__ u16 Bs[4][128 * 32];
  const int tid = threadIdx.x;
  const int lane = tid & 63;
  const int wid = tid >> 6;
  const int wr = wid >> 1, wc = wid & 1;
  const int rowA0 = blockIdx.y * 128, colB0 = blockIdx.x * 128;
  const int lr = lane & 15;
  const int lg = lane >> 4;
  const int lk = lg * 8;
  const char* Ab = (const char*)A;
  const char* Bb = (const char*)Bm;
  f32x4 acc[4][4] = {};
  const int nkt = K >> 5;

  auto STAGE = [&](int kt, int buf) {
#pragma unroll
    for (int p = 0; p < 2; ++p) {
      int o = p * 4096 + tid * 16;
      int row = o >> 6, kb = o & 63;
      gload_lds16(Ab + ((size_t)(rowA0 + row) * K + kt * 32) * 2 + kb, (char*)As[buf] + o);
      gload_lds16(Bb + ((size_t)(colB0 + row) * K + kt * 32) * 2 + kb, (char*)Bs[buf] + o);
    }
  };

  STAGE(0, 0);
  STAGE(1, 1);
  for (int kt = 0; kt < nkt; ++kt) {
    const int cur = kt & 3;
    if (kt + 2 < nkt)      { STAGE(kt + 2, (kt + 2) & 3); WAITVM(8); }
    else if (kt + 1 < nkt) { WAITVM(4); }
    else                   { WAITVM(0); }
    __builtin_amdgcn_s_barrier();
    MEMFENCE;
    const u16* Ac = As[cur];
    const u16* Bc = Bs[cur];
    bf16x8 af[4], bfr[4];
#pragma unroll
    for (int m = 0; m < 4; ++m)
      af[m] = *(const bf16x8*)&Ac[(wr * 64 + m * 16 + lr) * 32 + lk];
#pragma unroll
    for (int n = 0; n < 4; ++n)
      bfr[n] = *(const bf16x8*)&Bc[(wc * 64 + n * 16 + lr) * 32 + lk];
    __builtin_amdgcn_s_setprio(1);
#pragma unroll
    for (int m = 0; m < 4; ++m)
#pragma unroll
      for (int n = 0; n < 4; ++n)
        acc[m][n] = __builtin_amdgcn_mfma_f32_16x16x32_bf16(af[m], bfr[n], acc[m][n], 0, 0, 0);
    __builtin_amdgcn_s_setprio(0);
    MEMFENCE;
  }

  if (MODE == 0) {
#pragma unroll
    for (int m = 0; m < 4; ++m) {
      int row0 = rowA0 + wr * 64 + m * 16 + lg * 4;
#pragma unroll
      for (int n = 0; n < 4; ++n) {
        int col = colB0 + wc * 64 + n * 16 + lr;
#pragma unroll
        for (int r = 0; r < 4; ++r)
          ((float*)Cv)[(size_t)(row0 + r) * N + col] = acc[m][n][r];
      }
    }
  } else {
    // fused RoPE/split epilogue. colblk<16: Q head; 16..19: K head; 20..23: V.
    const int colblk = colB0 >> 7;
#pragma unroll
    for (int m = 0; m < 4; ++m) {
      int row0 = rowA0 + wr * 64 + m * 16 + lg * 4;  // 4 consecutive tokens
      int b_ = row0 >> 11;
      int s0 = row0 & 2047;
#pragma unroll
      for (int n = 0; n < 4; ++n) {
        int d = wc * 64 + n * 16 + lr;               // 0..127
        f32x4 v = acc[m][n];
        if (colblk < 20) {
          f32x4 pw;
#pragma unroll
          for (int r = 0; r < 4; ++r) pw[r] = __shfl_xor(v[r], 1, 64);
          int p = d >> 1;
          const bool ev = !(d & 1);
#pragma unroll
          for (int r = 0; r < 4; ++r) {
            int st = s0 + r;
            float c = fc[(st * 64 + p) * 2];
            float sn = fc[(st * 64 + p) * 2 + 1];
            float res = ev ? (v[r] * c - pw[r] * sn) : (v[r] * c + pw[r] * sn);
            if (colblk < 16)
              Qb[((size_t)(b_ * NH + colblk) * NS + st) * HDIM + d] = f2bf(res);
            else
              Kb[((size_t)(b_ * NKVH + (colblk - 16)) * NS + st) * HDIM + d] =
                  f2bf(res * QK_SCALE);
          }
        } else {
          int kv = colblk - 20;
          union { u16 h[4]; uint2 u; } o;
#pragma unroll
          for (int r = 0; r < 4; ++r) o.h[r] = f2bf(v[r]);
          *(uint2*)&Vt[((size_t)(b_ * NKVH + kv) * HDIM + d) * NS + s0] = o.u;
        }
      }
    }
  }
}

// ---------------- causal flash attention, QBLK=128, KBLK=64, 8 waves ------
// Triple-buffered K/V (96 KB — free, since 1 block/CU at any LDS size per
// R6/R8/R12 evidence): one barrier per k-round, no end-of-round drain.
// Uniform-cost blocks (q-tiles pair and 15-pair). Swapped QK^T; in-register
// P crossbar; counted vmcnt. (R14 structure — unchanged.)
__global__ __launch_bounds__(512, 2)
void flash_attn(const u16* __restrict__ Qb, const u16* __restrict__ Kb,
                const u16* __restrict__ Vt, u16* __restrict__ Ob) {
  __shared__ u16 Ks[3][64 * 128];   // K rows: 256B, XOR-swizzled
  __shared__ u16 Vs[3][128 * 64];   // V^T rows: 128B, XOR-swizzled
  const int idx = blockIdx.x;
  const int grp = idx & 7;               // XCD id = (b, kvh)
  const int b = grp >> 2, kvh = grp & 3;
  const int rest = idx >> 3;             // 0..31
  const int h = kvh * 4 + (rest & 3);
  const int pair = rest >> 2;            // 0..7
  const int tid = threadIdx.x, lane = tid & 63, w = tid >> 6;
  const int lr = lane & 15, lg = lane >> 4;

  bf16x8 ones;
#pragma unroll
  for (int j = 0; j < 8; ++j) ones[j] = (short)0x3F80;  // bf16 1.0

  const char* Kbase = (const char*)(Kb + (size_t)(b * NKVH + kvh) * NS * HDIM);
  const char* Vbase = (const char*)(Vt + (size_t)(b * NKVH + kvh) * HDIM * NS);

  auto STAGE = [&](int kt, int buf) {
#pragma unroll
    for (int p = 0; p < 2; ++p) {
      int o = p * 8192 + tid * 16;
      int krow = o >> 8, kwb = o & 255;
      gload_lds16(Kbase + (size_t)(kt * 64 + krow) * 256 + (kwb ^ ((krow & 7) << 4)),
                  (char*)Ks[buf] + o);
      int vrow = o >> 7, vwb = o & 127;
      gload_lds16(Vbase + (size_t)vrow * (NS * 2) + kt * 128 + (vwb ^ ((vrow & 7) << 4)),
                  (char*)Vs[buf] + o);
    }
  };

  for (int t = 0; t < 2; ++t) {
    const int qt = t ? (NS / 128 - 1 - pair) : pair;

    // protect buffer reuse across the t-boundary (and harmless at t=0)
    __builtin_amdgcn_s_barrier();
    MEMFENCE;

    // Q as MFMA B-fragment: lane holds Q[q = w*16+lr][d = ks*32 + lg*8 + j]
    bf16x8 aq[4];
    {
      const u16* Qrow = Qb + ((size_t)(b * NH + h) * NS + qt * 128 + w * 16 + lr) * HDIM;
#pragma unroll
      for (int ks = 0; ks < 4; ++ks)
        aq[ks] = *(const bf16x8*)(Qrow + ks * 32 + lg * 8);
    }

    float mrun = -1e30f;            // running max for q = w*16+lr (log2 dom.)
    f32x4 accl = {0.f, 0.f, 0.f, 0.f};
    f32x4 acco[8] = {};

    const int qglob = qt * 128 + w * 16 + lr;       // this lane's q row
    const int qrow0 = qt * 128 + w * 16 + lg * 4;   // acco row base
    const int wave_min_row = qt * 128 + w * 16;
    const int wave_max_row = wave_min_row + 15;

    const int ktmax = 2 * qt + 1;
    STAGE(0, 0);
    int cur = 0;
    for (int kt = 0; kt <= ktmax; ++kt) {
      const int nxt = (cur == 2) ? 0 : cur + 1;
      if (kt < ktmax) { STAGE(kt + 1, nxt); WAITVM(4); }
      else            { WAITVM(0); }
      __builtin_amdgcn_s_barrier();
      MEMFENCE;

      // waves whose rows are all above this k-tile skip compute
      if (kt * 64 <= wave_max_row) {
        const char* Kc = (const char*)Ks[cur];
        const char* Vc = (const char*)Vs[cur];

        // S^T = K·Q^T: accs[n] holds S[q = w16+lr][k = kt*64 + n*16 + lg*4 + r]
        f32x4 accs[4] = {};
        __builtin_amdgcn_s_setprio(1);
#pragma unroll
        for (int n = 0; n < 4; ++n) {
          int row = n * 16 + lr;
          int swz = (row & 7) << 4;
#pragma unroll
          for (int ks = 0; ks < 4; ++ks) {
            int cb = (ks * 32 + lg * 8) * 2;
            bf16x8 bk = *(const bf16x8*)(Kc + row * 256 + (cb ^ swz));
            accs[n] = __builtin_amdgcn_mfma_f32_16x16x32_bf16(bk, aq[ks], accs[n], 0, 0, 0);
          }
        }
        __builtin_amdgcn_s_setprio(0);

        if (kt * 64 + 63 > wave_min_row) {   // diagonal tile for this wave
#pragma unroll
          for (int n = 0; n < 4; ++n) {
            int kbase = kt * 64 + n * 16 + lg * 4;
#pragma unroll
            for (int r = 0; r < 4; ++r)
              if (kbase + r > qglob) accs[n][r] = -1e30f;
          }
        }

        // row max over 64 k: 16 in-lane values + 2 cross-lane rounds
        float pmax = fmaxf(fmaxf(fmaxf(accs[0][0], accs[0][1]), fmaxf(accs[0][2], accs[0][3])),
                           fmaxf(fmaxf(accs[1][0], accs[1][1]), fmaxf(accs[1][2], accs[1][3])));
        pmax = fmaxf(pmax,
               fmaxf(fmaxf(fmaxf(accs[2][0], accs[2][1]), fmaxf(accs[2][2], accs[2][3])),
                     fmaxf(fmaxf(accs[3][0], accs[3][1]), fmaxf(accs[3][2], accs[3][3]))));
        pmax = fmaxf(pmax, __shfl_xor(pmax, 16, 64));
        pmax = fmaxf(pmax, __shfl_xor(pmax, 32, 64));

        // defer-max: rescale only when some row's max grew by > 8 (log2 units)
        bool ok = (pmax <= mrun + 8.f);
        if (!__all(ok)) {
          float mnew = fmaxf(mrun, pmax);
          float alpha = exp2f(mrun - mnew);
          mrun = mnew;
          float alr[4];
#pragma unroll
          for (int r = 0; r < 4; ++r)
            alr[r] = __shfl(alpha, lg * 4 + r, 64);
#pragma unroll
          for (int r = 0; r < 4; ++r) accl[r] *= alr[r];
#pragma unroll
          for (int n2 = 0; n2 < 8; ++n2)
#pragma unroll
            for (int r = 0; r < 4; ++r) acco[n2][r] *= alr[r];
        }

        // P = exp2(S - m); pack to bf16 dwords: w0[n]={r0,r1}, w1[n]={r2,r3}
        uint32_t w0[4], w1[4];
#pragma unroll
        for (int n = 0; n < 4; ++n) {
          float p0 = exp2f(accs[n][0] - mrun);
          float p1 = exp2f(accs[n][1] - mrun);
          float p2 = exp2f(accs[n][2] - mrun);
          float p3 = exp2f(accs[n][3] - mrun);
          w0[n] = cvt_pk_bf16(p0, p1);
          w1[n] = cvt_pk_bf16(p2, p3);
        }

        // Redistribute P to PV A-fragment layout (in-register crossbar)
        const int s1 = ((lg & 1) << 5) | lr;
        const int s2 = s1 + 16;
        uint32_t F[4][4];
#pragma unroll
        for (int n = 0; n < 4; ++n) {
          F[n][0] = __shfl((int)w0[n], s1, 64);
          F[n][1] = __shfl((int)w1[n], s1, 64);
          F[n][2] = __shfl((int)w0[n], s2, 64);
          F[n][3] = __shfl((int)w1[n], s2, 64);
        }
        const bool hi = (lg & 2);
        bf16x8 pa[2];
#pragma unroll
        for (int ks = 0; ks < 2; ++ks) {
          union { uint32_t d[4]; bf16x8 v; } u;
#pragma unroll
          for (int j = 0; j < 4; ++j)
            u.d[j] = hi ? F[ks * 2 + 1][j] : F[ks * 2][j];
          pa[ks] = u.v;
        }

        // PV: out[16 q][128 d] += P[16 q][64 k] * V[64 k][128 d]; l += P*ones
        __builtin_amdgcn_s_setprio(1);
#pragma unroll
        for (int ks = 0; ks < 2; ++ks) {
          int cb = (ks * 32 + lg * 8) * 2;
#pragma unroll
          for (int n2 = 0; n2 < 8; ++n2) {
            int d = n2 * 16 + lr;
            bf16x8 bv = *(const bf16x8*)(Vc + d * 128 + (cb ^ ((d & 7) << 4)));
            acco[n2] = __builtin_amdgcn_mfma_f32_16x16x32_bf16(pa[ks], bv, acco[n2], 0, 0, 0);
          }
          accl = __builtin_amdgcn_mfma_f32_16x16x32_bf16(pa[ks], ones, accl, 0, 0, 0);
        }
        __builtin_amdgcn_s_setprio(0);
      }
      MEMFENCE;
      cur = nxt;
    }

    // epilogue: attn_out[b][s][h][d] (bf16)
#pragma unroll
    for (int n2 = 0; n2 < 8; ++n2) {
      int d = n2 * 16 + lr;
#pragma unroll
      for (int r = 0; r < 4; ++r) {
        int q = qrow0 + r;
        Ob[((size_t)b * NS + q) * ND + h * HDIM + d] = f2bf(acco[n2][r] / accl[r]);
      }
    }
  }
}

extern "C" void kernel_launch(void* const* d_in, const int* in_sizes, int n_in,
                              void* d_out, int out_size, void* d_ws, size_t ws_size,
                              hipStream_t stream) {
  const float* x = (const float*)d_in[0];
  const float* fc = (const float*)d_in[1];
  const float* wqkv = (const float*)d_in[2];
  const float* wo = (const float*)d_in[3];
  float* out = (float*)d_out;
  char* ws = (char*)d_ws;
  size_t off = 0;
  u16* xb = (u16*)(ws + off);    off += (size_t)TOK * ND * 2;
  u16* wqkvb = (u16*)(ws + off); off += (size_t)QKVD * ND * 2;
  u16* wob = (u16*)(ws + off);   off += (size_t)ND * ND * 2;
  u16* Qb = (u16*)(ws + off);    off += (size_t)NB * NH * NS * HDIM * 2;
  u16* Kb = (u16*)(ws + off);    off += (size_t)NB * NKVH * NS * HDIM * 2;
  u16* Vtb = (u16*)(ws + off);   off += (size_t)NB * NKVH * NS * HDIM * 2;
  u16* attnb = (u16*)(ws + off); off += (size_t)TOK * ND * 2;
  (void)ws_size; (void)in_sizes; (void)n_in; (void)out_size;

  constexpr int CVTN = (TOK * ND + QKVD * ND + ND * ND) / 4;
  cvt3<<<CVTN / 256, 256, 0, stream>>>(x, wqkv, wo, xb, wqkvb, wob);
  gemm_bt<2><<<dim3(QKVD / 128, TOK / 128), 256, 0, stream>>>(
      xb, wqkvb, nullptr, TOK, QKVD, ND, fc, Qb, Kb, Vtb);
  flash_attn<<<dim3(256), 512, 0, stream>>>(Qb, Kb, Vtb, attnb);
  gemm_bt<0><<<dim3(ND / 128, TOK / 128), 256, 0, stream>>>(
      attnb, wob, out, TOK, ND, ND, nullptr, nullptr, nullptr, nullptr);
}

// Round 16
// 202.686 us; speedup vs baseline: 1.1073x; 1.1073x over previous
//
#include <hip/hip_runtime.h>
#include <stdint.h>

typedef uint16_t u16;
typedef float f32x4 __attribute__((ext_vector_type(4)));
typedef short bf16x8 __attribute__((ext_vector_type(8)));

constexpr int NB = 2, NS = 2048, ND = 2048, NH = 16, NKVH = 4, HDIM = 128;
constexpr int QKVD = 3072;
constexpr int TOK = NB * NS;
constexpr float SM_SCALE = 0.08838834764831845f; // 1/sqrt(128)
constexpr float LOG2E = 1.4426950408889634f;
constexpr float QK_SCALE = SM_SCALE * LOG2E;     // folded into K at rope time

#define WAITVM(N) asm volatile("s_waitcnt vmcnt(" #N ")" ::: "memory")
#define MEMFENCE asm volatile("" ::: "memory")

__device__ __forceinline__ u16 f2bf(float f) {
  union { float f; uint32_t u; } v; v.f = f;
  return (u16)((v.u + 0x7fffu + ((v.u >> 16) & 1u)) >> 16);
}
__device__ __forceinline__ uint32_t cvt_pk_bf16(float lo, float hi) {
  uint32_t r;
  asm("v_cvt_pk_bf16_f32 %0, %1, %2" : "=v"(r) : "v"(lo), "v"(hi));
  return r;
}

__device__ __forceinline__ void gload_lds16(const void* g, void* l) {
  void* gv = const_cast<void*>(g);
  __builtin_amdgcn_global_load_lds(
      (__attribute__((address_space(1))) void*)gv,
      (__attribute__((address_space(3))) void*)l, 16, 0, 0);
}

// ---------------- merged f32 -> bf16 conversion (3 tensors, 1 launch) ------
__global__ __launch_bounds__(256)
void cvt3(const float* __restrict__ x, const float* __restrict__ wq,
          const float* __restrict__ wo, u16* __restrict__ xb,
          u16* __restrict__ wqb, u16* __restrict__ wob) {
  constexpr int N1 = TOK * ND / 4, N2 = QKVD * ND / 4, N3 = ND * ND / 4;
  int i = blockIdx.x * 256 + threadIdx.x;
  const float* src; u16* dst; int j;
  if (i < N1)              { src = x;  dst = xb;  j = i; }
  else if (i < N1 + N2)    { src = wq; dst = wqb; j = i - N1; }
  else if (i < N1 + N2 + N3){ src = wo; dst = wob; j = i - N1 - N2; }
  else return;
  const float4 v = reinterpret_cast<const float4*>(src)[j];
  union { u16 h[4]; uint2 u; } o;
  o.h[0] = f2bf(v.x); o.h[1] = f2bf(v.y); o.h[2] = f2bf(v.z); o.h[3] = f2bf(v.w);
  reinterpret_cast<uint2*>(dst)[j] = o.u;
}

// ---------------- GEMM: C[M][N] = A[M][K] * B[N][K]^T (bf16 in) ------------
// Triple-buffered BK=32: STAGE(kt+1) writes buf (kt+1)%3 which no wave is
// reading, so only ONE barrier per K-tile (after the counted vmcnt gate) is
// needed — the end-of-round barrier + lgkm drain of the 2-buffer version are
// deleted. 48 KB LDS -> 3 blocks/CU possible. MODE 0: f32 out.
// MODE 2: fused RoPE/split epilogue.
template <int MODE>
__global__ __launch_bounds__(256, 2)
void gemm_bt(const u16* __restrict__ A, const u16* __restrict__ Bm,
             void* __restrict__ Cv, int M, int N, int K,
             const float* __restrict__ fc, u16* __restrict__ Qb,
             u16* __restrict__ Kb, u16* __restrict__ Vt) {
  __shared__ u16 As[3][128 * 32];
  __shared__ u16 Bs[3][128 * 32];
  const int tid = threadIdx.x;
  const int lane = tid & 63;
  const int wid = tid >> 6;
  const int wr = wid >> 1, wc = wid & 1;
  const int rowA0 = blockIdx.y * 128, colB0 = blockIdx.x * 128;
  const int lr = lane & 15;
  const int lg = lane >> 4;
  const int lk = lg * 8;
  const char* Ab = (const char*)A;
  const char* Bb = (const char*)Bm;
  f32x4 acc[4][4] = {};
  const int nkt = K >> 5;

  auto STAGE = [&](int kt, int buf) {
#pragma unroll
    for (int p = 0; p < 2; ++p) {
      int o = p * 4096 + tid * 16;
      int row = o >> 6, kb = o & 63;
      gload_lds16(Ab + ((size_t)(rowA0 + row) * K + kt * 32) * 2 + kb, (char*)As[buf] + o);
      gload_lds16(Bb + ((size_t)(colB0 + row) * K + kt * 32) * 2 + kb, (char*)Bs[buf] + o);
    }
  };

  STAGE(0, 0);
  int cur = 0;
  for (int kt = 0; kt < nkt; ++kt) {
    const int nxt = (cur == 2) ? 0 : cur + 1;
    if (kt + 1 < nkt) { STAGE(kt + 1, nxt); WAITVM(4); }
    else              { WAITVM(0); }
    __builtin_amdgcn_s_barrier();
    MEMFENCE;
    const u16* Ac = As[cur];
    const u16* Bc = Bs[cur];
    bf16x8 af[4], bfr[4];
#pragma unroll
    for (int m = 0; m < 4; ++m)
      af[m] = *(const bf16x8*)&Ac[(wr * 64 + m * 16 + lr) * 32 + lk];
#pragma unroll
    for (int n = 0; n < 4; ++n)
      bfr[n] = *(const bf16x8*)&Bc[(wc * 64 + n * 16 + lr) * 32 + lk];
    __builtin_amdgcn_s_setprio(1);
#pragma unroll
    for (int m = 0; m < 4; ++m)
#pragma unroll
      for (int n = 0; n < 4; ++n)
        acc[m][n] = __builtin_amdgcn_mfma_f32_16x16x32_bf16(af[m], bfr[n], acc[m][n], 0, 0, 0);
    __builtin_amdgcn_s_setprio(0);
    MEMFENCE;
    cur = nxt;
  }

  if (MODE == 0) {
#pragma unroll
    for (int m = 0; m < 4; ++m) {
      int row0 = rowA0 + wr * 64 + m * 16 + lg * 4;
#pragma unroll
      for (int n = 0; n < 4; ++n) {
        int col = colB0 + wc * 64 + n * 16 + lr;
#pragma unroll
        for (int r = 0; r < 4; ++r)
          ((float*)Cv)[(size_t)(row0 + r) * N + col] = acc[m][n][r];
      }
    }
  } else {
    // fused RoPE/split epilogue. colblk<16: Q head; 16..19: K head; 20..23: V.
    const int colblk = colB0 >> 7;
#pragma unroll
    for (int m = 0; m < 4; ++m) {
      int row0 = rowA0 + wr * 64 + m * 16 + lg * 4;  // 4 consecutive tokens
      int b_ = row0 >> 11;
      int s0 = row0 & 2047;
#pragma unroll
      for (int n = 0; n < 4; ++n) {
        int d = wc * 64 + n * 16 + lr;               // 0..127
        f32x4 v = acc[m][n];
        if (colblk < 20) {
          f32x4 pw;
#pragma unroll
          for (int r = 0; r < 4; ++r) pw[r] = __shfl_xor(v[r], 1, 64);
          int p = d >> 1;
          const bool ev = !(d & 1);
#pragma unroll
          for (int r = 0; r < 4; ++r) {
            int st = s0 + r;
            float c = fc[(st * 64 + p) * 2];
            float sn = fc[(st * 64 + p) * 2 + 1];
            float res = ev ? (v[r] * c - pw[r] * sn) : (v[r] * c + pw[r] * sn);
            if (colblk < 16)
              Qb[((size_t)(b_ * NH + colblk) * NS + st) * HDIM + d] = f2bf(res);
            else
              Kb[((size_t)(b_ * NKVH + (colblk - 16)) * NS + st) * HDIM + d] =
                  f2bf(res * QK_SCALE);
          }
        } else {
          int kv = colblk - 20;
          union { u16 h[4]; uint2 u; } o;
#pragma unroll
          for (int r = 0; r < 4; ++r) o.h[r] = f2bf(v[r]);
          *(uint2*)&Vt[((size_t)(b_ * NKVH + kv) * HDIM + d) * NS + s0] = o.u;
        }
      }
    }
  }
}

// ---------------- causal flash attention, QBLK=128, KBLK=64, 8 waves ------
// Triple-buffered K/V (96 KB — free, since 1 block/CU at any LDS size per
// R6/R8/R12 evidence): one barrier per k-round, no end-of-round drain.
// Uniform-cost blocks (q-tiles pair and 15-pair). Swapped QK^T; in-register
// P crossbar; counted vmcnt. (R14 structure — unchanged.)
__global__ __launch_bounds__(512, 2)
void flash_attn(const u16* __restrict__ Qb, const u16* __restrict__ Kb,
                const u16* __restrict__ Vt, u16* __restrict__ Ob) {
  __shared__ u16 Ks[3][64 * 128];   // K rows: 256B, XOR-swizzled
  __shared__ u16 Vs[3][128 * 64];   // V^T rows: 128B, XOR-swizzled
  const int idx = blockIdx.x;
  const int grp = idx & 7;               // XCD id = (b, kvh)
  const int b = grp >> 2, kvh = grp & 3;
  const int rest = idx >> 3;             // 0..31
  const int h = kvh * 4 + (rest & 3);
  const int pair = rest >> 2;            // 0..7
  const int tid = threadIdx.x, lane = tid & 63, w = tid >> 6;
  const int lr = lane & 15, lg = lane >> 4;

  bf16x8 ones;
#pragma unroll
  for (int j = 0; j < 8; ++j) ones[j] = (short)0x3F80;  // bf16 1.0

  const char* Kbase = (const char*)(Kb + (size_t)(b * NKVH + kvh) * NS * HDIM);
  const char* Vbase = (const char*)(Vt + (size_t)(b * NKVH + kvh) * HDIM * NS);

  auto STAGE = [&](int kt, int buf) {
#pragma unroll
    for (int p = 0; p < 2; ++p) {
      int o = p * 8192 + tid * 16;
      int krow = o >> 8, kwb = o & 255;
      gload_lds16(Kbase + (size_t)(kt * 64 + krow) * 256 + (kwb ^ ((krow & 7) << 4)),
                  (char*)Ks[buf] + o);
      int vrow = o >> 7, vwb = o & 127;
      gload_lds16(Vbase + (size_t)vrow * (NS * 2) + kt * 128 + (vwb ^ ((vrow & 7) << 4)),
                  (char*)Vs[buf] + o);
    }
  };

  for (int t = 0; t < 2; ++t) {
    const int qt = t ? (NS / 128 - 1 - pair) : pair;

    // protect buffer reuse across the t-boundary (and harmless at t=0)
    __builtin_amdgcn_s_barrier();
    MEMFENCE;

    // Q as MFMA B-fragment: lane holds Q[q = w*16+lr][d = ks*32 + lg*8 + j]
    bf16x8 aq[4];
    {
      const u16* Qrow = Qb + ((size_t)(b * NH + h) * NS + qt * 128 + w * 16 + lr) * HDIM;
#pragma unroll
      for (int ks = 0; ks < 4; ++ks)
        aq[ks] = *(const bf16x8*)(Qrow + ks * 32 + lg * 8);
    }

    float mrun = -1e30f;            // running max for q = w*16+lr (log2 dom.)
    f32x4 accl = {0.f, 0.f, 0.f, 0.f};
    f32x4 acco[8] = {};

    const int qglob = qt * 128 + w * 16 + lr;       // this lane's q row
    const int qrow0 = qt * 128 + w * 16 + lg * 4;   // acco row base
    const int wave_min_row = qt * 128 + w * 16;
    const int wave_max_row = wave_min_row + 15;

    const int ktmax = 2 * qt + 1;
    STAGE(0, 0);
    int cur = 0;
    for (int kt = 0; kt <= ktmax; ++kt) {
      const int nxt = (cur == 2) ? 0 : cur + 1;
      if (kt < ktmax) { STAGE(kt + 1, nxt); WAITVM(4); }
      else            { WAITVM(0); }
      __builtin_amdgcn_s_barrier();
      MEMFENCE;

      // waves whose rows are all above this k-tile skip compute
      if (kt * 64 <= wave_max_row) {
        const char* Kc = (const char*)Ks[cur];
        const char* Vc = (const char*)Vs[cur];

        // S^T = K·Q^T: accs[n] holds S[q = w16+lr][k = kt*64 + n*16 + lg*4 + r]
        f32x4 accs[4] = {};
        __builtin_amdgcn_s_setprio(1);
#pragma unroll
        for (int n = 0; n < 4; ++n) {
          int row = n * 16 + lr;
          int swz = (row & 7) << 4;
#pragma unroll
          for (int ks = 0; ks < 4; ++ks) {
            int cb = (ks * 32 + lg * 8) * 2;
            bf16x8 bk = *(const bf16x8*)(Kc + row * 256 + (cb ^ swz));
            accs[n] = __builtin_amdgcn_mfma_f32_16x16x32_bf16(bk, aq[ks], accs[n], 0, 0, 0);
          }
        }
        __builtin_amdgcn_s_setprio(0);

        if (kt * 64 + 63 > wave_min_row) {   // diagonal tile for this wave
#pragma unroll
          for (int n = 0; n < 4; ++n) {
            int kbase = kt * 64 + n * 16 + lg * 4;
#pragma unroll
            for (int r = 0; r < 4; ++r)
              if (kbase + r > qglob) accs[n][r] = -1e30f;
          }
        }

        // row max over 64 k: 16 in-lane values + 2 cross-lane rounds
        float pmax = fmaxf(fmaxf(fmaxf(accs[0][0], accs[0][1]), fmaxf(accs[0][2], accs[0][3])),
                           fmaxf(fmaxf(accs[1][0], accs[1][1]), fmaxf(accs[1][2], accs[1][3])));
        pmax = fmaxf(pmax,
               fmaxf(fmaxf(fmaxf(accs[2][0], accs[2][1]), fmaxf(accs[2][2], accs[2][3])),
                     fmaxf(fmaxf(accs[3][0], accs[3][1]), fmaxf(accs[3][2], accs[3][3]))));
        pmax = fmaxf(pmax, __shfl_xor(pmax, 16, 64));
        pmax = fmaxf(pmax, __shfl_xor(pmax, 32, 64));

        // defer-max: rescale only when some row's max grew by > 8 (log2 units)
        bool ok = (pmax <= mrun + 8.f);
        if (!__all(ok)) {
          float mnew = fmaxf(mrun, pmax);
          float alpha = exp2f(mrun - mnew);
          mrun = mnew;
          float alr[4];
#pragma unroll
          for (int r = 0; r < 4; ++r)
            alr[r] = __shfl(alpha, lg * 4 + r, 64);
#pragma unroll
          for (int r = 0; r < 4; ++r) accl[r] *= alr[r];
#pragma unroll
          for (int n2 = 0; n2 < 8; ++n2)
#pragma unroll
            for (int r = 0; r < 4; ++r) acco[n2][r] *= alr[r];
        }

        // P = exp2(S - m); pack to bf16 dwords: w0[n]={r0,r1}, w1[n]={r2,r3}
        uint32_t w0[4], w1[4];
#pragma unroll
        for (int n = 0; n < 4; ++n) {
          float p0 = exp2f(accs[n][0] - mrun);
          float p1 = exp2f(accs[n][1] - mrun);
          float p2 = exp2f(accs[n][2] - mrun);
          float p3 = exp2f(accs[n][3] - mrun);
          w0[n] = cvt_pk_bf16(p0, p1);
          w1[n] = cvt_pk_bf16(p2, p3);
        }

        // Redistribute P to PV A-fragment layout (in-register crossbar)
        const int s1 = ((lg & 1) << 5) | lr;
        const int s2 = s1 + 16;
        uint32_t F[4][4];
#pragma unroll
        for (int n = 0; n < 4; ++n) {
          F[n][0] = __shfl((int)w0[n], s1, 64);
          F[n][1] = __shfl((int)w1[n], s1, 64);
          F[n][2] = __shfl((int)w0[n], s2, 64);
          F[n][3] = __shfl((int)w1[n], s2, 64);
        }
        const bool hi = (lg & 2);
        bf16x8 pa[2];
#pragma unroll
        for (int ks = 0; ks < 2; ++ks) {
          union { uint32_t d[4]; bf16x8 v; } u;
#pragma unroll
          for (int j = 0; j < 4; ++j)
            u.d[j] = hi ? F[ks * 2 + 1][j] : F[ks * 2][j];
          pa[ks] = u.v;
        }

        // PV: out[16 q][128 d] += P[16 q][64 k] * V[64 k][128 d]; l += P*ones
        __builtin_amdgcn_s_setprio(1);
#pragma unroll
        for (int ks = 0; ks < 2; ++ks) {
          int cb = (ks * 32 + lg * 8) * 2;
#pragma unroll
          for (int n2 = 0; n2 < 8; ++n2) {
            int d = n2 * 16 + lr;
            bf16x8 bv = *(const bf16x8*)(Vc + d * 128 + (cb ^ ((d & 7) << 4)));
            acco[n2] = __builtin_amdgcn_mfma_f32_16x16x32_bf16(pa[ks], bv, acco[n2], 0, 0, 0);
          }
          accl = __builtin_amdgcn_mfma_f32_16x16x32_bf16(pa[ks], ones, accl, 0, 0, 0);
        }
        __builtin_amdgcn_s_setprio(0);
      }
      MEMFENCE;
      cur = nxt;
    }

    // epilogue: attn_out[b][s][h][d] (bf16)
#pragma unroll
    for (int n2 = 0; n2 < 8; ++n2) {
      int d = n2 * 16 + lr;
#pragma unroll
      for (int r = 0; r < 4; ++r) {
        int q = qrow0 + r;
        Ob[((size_t)b * NS + q) * ND + h * HDIM + d] = f2bf(acco[n2][r] / accl[r]);
      }
    }
  }
}

extern "C" void kernel_launch(void* const* d_in, const int* in_sizes, int n_in,
                              void* d_out, int out_size, void* d_ws, size_t ws_size,
                              hipStream_t stream) {
  const float* x = (const float*)d_in[0];
  const float* fc = (const float*)d_in[1];
  const float* wqkv = (const float*)d_in[2];
  const float* wo = (const float*)d_in[3];
  float* out = (float*)d_out;
  char* ws = (char*)d_ws;
  size_t off = 0;
  u16* xb = (u16*)(ws + off);    off += (size_t)TOK * ND * 2;
  u16* wqkvb = (u16*)(ws + off); off += (size_t)QKVD * ND * 2;
  u16* wob = (u16*)(ws + off);   off += (size_t)ND * ND * 2;
  u16* Qb = (u16*)(ws + off);    off += (size_t)NB * NH * NS * HDIM * 2;
  u16* Kb = (u16*)(ws + off);    off += (size_t)NB * NKVH * NS * HDIM * 2;
  u16* Vtb = (u16*)(ws + off);   off += (size_t)NB * NKVH * NS * HDIM * 2;
  u16* attnb = (u16*)(ws + off); off += (size_t)TOK * ND * 2;
  (void)ws_size; (void)in_sizes; (void)n_in; (void)out_size;

  constexpr int CVTN = (TOK * ND + QKVD * ND + ND * ND) / 4;
  cvt3<<<CVTN / 256, 256, 0, stream>>>(x, wqkv, wo, xb, wqkvb, wob);
  gemm_bt<2><<<dim3(QKVD / 128, TOK / 128), 256, 0, stream>>>(
      xb, wqkvb, nullptr, TOK, QKVD, ND, fc, Qb, Kb, Vtb);
  flash_attn<<<dim3(256), 512, 0, stream>>>(Qb, Kb, Vtb, attnb);
  gemm_bt<0><<<dim3(ND / 128, TOK / 128), 256, 0, stream>>>(
      attnb, wob, out, TOK, ND, ND, nullptr, nullptr, nullptr, nullptr);
}

// Round 17
// 197.192 us; speedup vs baseline: 1.1382x; 1.0279x over previous
//
#include <hip/hip_runtime.h>
#include <stdint.h>

typedef uint16_t u16;
typedef float f32x4 __attribute__((ext_vector_type(4)));
typedef short bf16x8 __attribute__((ext_vector_type(8)));

constexpr int NB = 2, NS = 2048, ND = 2048, NH = 16, NKVH = 4, HDIM = 128;
constexpr int QKVD = 3072;
constexpr int TOK = NB * NS;
constexpr float SM_SCALE = 0.08838834764831845f; // 1/sqrt(128)
constexpr float LOG2E = 1.4426950408889634f;
constexpr float QK_SCALE = SM_SCALE * LOG2E;     // folded into K at rope time

#define WAITVM(N) asm volatile("s_waitcnt vmcnt(" #N ")" ::: "memory")
#define MEMFENCE asm volatile("" ::: "memory")

__device__ __forceinline__ u16 f2bf(float f) {
  union { float f; uint32_t u; } v; v.f = f;
  return (u16)((v.u + 0x7fffu + ((v.u >> 16) & 1u)) >> 16);
}
__device__ __forceinline__ uint32_t cvt_pk_bf16(float lo, float hi) {
  uint32_t r;
  asm("v_cvt_pk_bf16_f32 %0, %1, %2" : "=v"(r) : "v"(lo), "v"(hi));
  return r;
}

__device__ __forceinline__ void gload_lds16(const void* g, void* l) {
  void* gv = const_cast<void*>(g);
  __builtin_amdgcn_global_load_lds(
      (__attribute__((address_space(1))) void*)gv,
      (__attribute__((address_space(3))) void*)l, 16, 0, 0);
}

// ---------------- merged f32 -> bf16 conversion (3 tensors, 1 launch) ------
__global__ __launch_bounds__(256)
void cvt3(const float* __restrict__ x, const float* __restrict__ wq,
          const float* __restrict__ wo, u16* __restrict__ xb,
          u16* __restrict__ wqb, u16* __restrict__ wob) {
  constexpr int N1 = TOK * ND / 4, N2 = QKVD * ND / 4, N3 = ND * ND / 4;
  int i = blockIdx.x * 256 + threadIdx.x;
  const float* src; u16* dst; int j;
  if (i < N1)              { src = x;  dst = xb;  j = i; }
  else if (i < N1 + N2)    { src = wq; dst = wqb; j = i - N1; }
  else if (i < N1 + N2 + N3){ src = wo; dst = wob; j = i - N1 - N2; }
  else return;
  const float4 v = reinterpret_cast<const float4*>(src)[j];
  union { u16 h[4]; uint2 u; } o;
  o.h[0] = f2bf(v.x); o.h[1] = f2bf(v.y); o.h[2] = f2bf(v.z); o.h[3] = f2bf(v.w);
  reinterpret_cast<uint2*>(dst)[j] = o.u;
}

// ---------------- GEMM: C[M][N] = A[M][K] * B[N][K]^T (bf16 in) ------------
// Triple-buffered BK=32, one barrier per K-tile (R14 structure).
// T1 XCD-aware chunked tile remap: orig dispatch idx round-robins XCDs, so
// tile = (idx%8)*(nwg/8) + idx/8 gives each XCD a contiguous tile chunk
// (shares A row-panels within one L2). nwg%8==0 for both grids -> bijective.
// MODE 0: f32 out. MODE 2: fused RoPE/split epilogue.
template <int MODE>
__global__ __launch_bounds__(256, 2)
void gemm_bt(const u16* __restrict__ A, const u16* __restrict__ Bm,
             void* __restrict__ Cv, int M, int N, int K,
             const float* __restrict__ fc, u16* __restrict__ Qb,
             u16* __restrict__ Kb, u16* __restrict__ Vt) {
  __shared__ u16 As[3][128 * 32];
  __shared__ u16 Bs[3][128 * 32];
  const int tid = threadIdx.x;
  const int lane = tid & 63;
  const int wid = tid >> 6;
  const int wr = wid >> 1, wc = wid & 1;
  const int gx = gridDim.x;
  const int idx0 = blockIdx.y * gx + blockIdx.x;
  const int nq = (gx * gridDim.y) >> 3;
  const int tile = (idx0 & 7) * nq + (idx0 >> 3);
  const int rowA0 = (tile / gx) * 128, colB0 = (tile % gx) * 128;
  const int lr = lane & 15;
  const int lg = lane >> 4;
  const int lk = lg * 8;
  const char* Ab = (const char*)A;
  const char* Bb = (const char*)Bm;
  f32x4 acc[4][4] = {};
  const int nkt = K >> 5;

  auto STAGE = [&](int kt, int buf) {
#pragma unroll
    for (int p = 0; p < 2; ++p) {
      int o = p * 4096 + tid * 16;
      int row = o >> 6, kb = o & 63;
      gload_lds16(Ab + ((size_t)(rowA0 + row) * K + kt * 32) * 2 + kb, (char*)As[buf] + o);
      gload_lds16(Bb + ((size_t)(colB0 + row) * K + kt * 32) * 2 + kb, (char*)Bs[buf] + o);
    }
  };

  STAGE(0, 0);
  int cur = 0;
  for (int kt = 0; kt < nkt; ++kt) {
    const int nxt = (cur == 2) ? 0 : cur + 1;
    if (kt + 1 < nkt) { STAGE(kt + 1, nxt); WAITVM(4); }
    else              { WAITVM(0); }
    __builtin_amdgcn_s_barrier();
    MEMFENCE;
    const u16* Ac = As[cur];
    const u16* Bc = Bs[cur];
    bf16x8 af[4], bfr[4];
#pragma unroll
    for (int m = 0; m < 4; ++m)
      af[m] = *(const bf16x8*)&Ac[(wr * 64 + m * 16 + lr) * 32 + lk];
#pragma unroll
    for (int n = 0; n < 4; ++n)
      bfr[n] = *(const bf16x8*)&Bc[(wc * 64 + n * 16 + lr) * 32 + lk];
    __builtin_amdgcn_s_setprio(1);
#pragma unroll
    for (int m = 0; m < 4; ++m)
#pragma unroll
      for (int n = 0; n < 4; ++n)
        acc[m][n] = __builtin_amdgcn_mfma_f32_16x16x32_bf16(af[m], bfr[n], acc[m][n], 0, 0, 0);
    __builtin_amdgcn_s_setprio(0);
    MEMFENCE;
    cur = nxt;
  }

  if (MODE == 0) {
#pragma unroll
    for (int m = 0; m < 4; ++m) {
      int row0 = rowA0 + wr * 64 + m * 16 + lg * 4;
#pragma unroll
      for (int n = 0; n < 4; ++n) {
        int col = colB0 + wc * 64 + n * 16 + lr;
#pragma unroll
        for (int r = 0; r < 4; ++r)
          ((float*)Cv)[(size_t)(row0 + r) * N + col] = acc[m][n][r];
      }
    }
  } else {
    // fused RoPE/split epilogue. colblk<16: Q head; 16..19: K head; 20..23: V.
    const int colblk = colB0 >> 7;
#pragma unroll
    for (int m = 0; m < 4; ++m) {
      int row0 = rowA0 + wr * 64 + m * 16 + lg * 4;  // 4 consecutive tokens
      int b_ = row0 >> 11;
      int s0 = row0 & 2047;
#pragma unroll
      for (int n = 0; n < 4; ++n) {
        int d = wc * 64 + n * 16 + lr;               // 0..127
        f32x4 v = acc[m][n];
        if (colblk < 20) {
          f32x4 pw;
#pragma unroll
          for (int r = 0; r < 4; ++r) pw[r] = __shfl_xor(v[r], 1, 64);
          int p = d >> 1;
          const bool ev = !(d & 1);
#pragma unroll
          for (int r = 0; r < 4; ++r) {
            int st = s0 + r;
            float c = fc[(st * 64 + p) * 2];
            float sn = fc[(st * 64 + p) * 2 + 1];
            float res = ev ? (v[r] * c - pw[r] * sn) : (v[r] * c + pw[r] * sn);
            if (colblk < 16)
              Qb[((size_t)(b_ * NH + colblk) * NS + st) * HDIM + d] = f2bf(res);
            else
              Kb[((size_t)(b_ * NKVH + (colblk - 16)) * NS + st) * HDIM + d] =
                  f2bf(res * QK_SCALE);
          }
        } else {
          int kv = colblk - 20;
          union { u16 h[4]; uint2 u; } o;
#pragma unroll
          for (int r = 0; r < 4; ++r) o.h[r] = f2bf(v[r]);
          *(uint2*)&Vt[((size_t)(b_ * NKVH + kv) * HDIM + d) * NS + s0] = o.u;
        }
      }
    }
  }
}

// ---------------- causal flash attention, QBLK=128, KBLK=64, 8 waves ------
// Triple-buffered K/V (96 KB): one barrier per k-round, no end-of-round
// drain. Uniform-cost blocks (q-tiles pair and 15-pair). Swapped QK^T;
// in-register P crossbar; counted vmcnt. (R14 structure — unchanged.)
__global__ __launch_bounds__(512, 2)
void flash_attn(const u16* __restrict__ Qb, const u16* __restrict__ Kb,
                const u16* __restrict__ Vt, u16* __restrict__ Ob) {
  __shared__ u16 Ks[3][64 * 128];   // K rows: 256B, XOR-swizzled
  __shared__ u16 Vs[3][128 * 64];   // V^T rows: 128B, XOR-swizzled
  const int idx = blockIdx.x;
  const int grp = idx & 7;               // XCD id = (b, kvh)
  const int b = grp >> 2, kvh = grp & 3;
  const int rest = idx >> 3;             // 0..31
  const int h = kvh * 4 + (rest & 3);
  const int pair = rest >> 2;            // 0..7
  const int tid = threadIdx.x, lane = tid & 63, w = tid >> 6;
  const int lr = lane & 15, lg = lane >> 4;

  bf16x8 ones;
#pragma unroll
  for (int j = 0; j < 8; ++j) ones[j] = (short)0x3F80;  // bf16 1.0

  const char* Kbase = (const char*)(Kb + (size_t)(b * NKVH + kvh) * NS * HDIM);
  const char* Vbase = (const char*)(Vt + (size_t)(b * NKVH + kvh) * HDIM * NS);

  auto STAGE = [&](int kt, int buf) {
#pragma unroll
    for (int p = 0; p < 2; ++p) {
      int o = p * 8192 + tid * 16;
      int krow = o >> 8, kwb = o & 255;
      gload_lds16(Kbase + (size_t)(kt * 64 + krow) * 256 + (kwb ^ ((krow & 7) << 4)),
                  (char*)Ks[buf] + o);
      int vrow = o >> 7, vwb = o & 127;
      gload_lds16(Vbase + (size_t)vrow * (NS * 2) + kt * 128 + (vwb ^ ((vrow & 7) << 4)),
                  (char*)Vs[buf] + o);
    }
  };

  for (int t = 0; t < 2; ++t) {
    const int qt = t ? (NS / 128 - 1 - pair) : pair;

    // protect buffer reuse across the t-boundary (and harmless at t=0)
    __builtin_amdgcn_s_barrier();
    MEMFENCE;

    // Q as MFMA B-fragment: lane holds Q[q = w*16+lr][d = ks*32 + lg*8 + j]
    bf16x8 aq[4];
    {
      const u16* Qrow = Qb + ((size_t)(b * NH + h) * NS + qt * 128 + w * 16 + lr) * HDIM;
#pragma unroll
      for (int ks = 0; ks < 4; ++ks)
        aq[ks] = *(const bf16x8*)(Qrow + ks * 32 + lg * 8);
    }

    float mrun = -1e30f;            // running max for q = w*16+lr (log2 dom.)
    f32x4 accl = {0.f, 0.f, 0.f, 0.f};
    f32x4 acco[8] = {};

    const int qglob = qt * 128 + w * 16 + lr;       // this lane's q row
    const int qrow0 = qt * 128 + w * 16 + lg * 4;   // acco row base
    const int wave_min_row = qt * 128 + w * 16;
    const int wave_max_row = wave_min_row + 15;

    const int ktmax = 2 * qt + 1;
    STAGE(0, 0);
    int cur = 0;
    for (int kt = 0; kt <= ktmax; ++kt) {
      const int nxt = (cur == 2) ? 0 : cur + 1;
      if (kt < ktmax) { STAGE(kt + 1, nxt); WAITVM(4); }
      else            { WAITVM(0); }
      __builtin_amdgcn_s_barrier();
      MEMFENCE;

      // waves whose rows are all above this k-tile skip compute
      if (kt * 64 <= wave_max_row) {
        const char* Kc = (const char*)Ks[cur];
        const char* Vc = (const char*)Vs[cur];

        // S^T = K·Q^T: accs[n] holds S[q = w16+lr][k = kt*64 + n*16 + lg*4 + r]
        f32x4 accs[4] = {};
        __builtin_amdgcn_s_setprio(1);
#pragma unroll
        for (int n = 0; n < 4; ++n) {
          int row = n * 16 + lr;
          int swz = (row & 7) << 4;
#pragma unroll
          for (int ks = 0; ks < 4; ++ks) {
            int cb = (ks * 32 + lg * 8) * 2;
            bf16x8 bk = *(const bf16x8*)(Kc + row * 256 + (cb ^ swz));
            accs[n] = __builtin_amdgcn_mfma_f32_16x16x32_bf16(bk, aq[ks], accs[n], 0, 0, 0);
          }
        }
        __builtin_amdgcn_s_setprio(0);

        if (kt * 64 + 63 > wave_min_row) {   // diagonal tile for this wave
#pragma unroll
          for (int n = 0; n < 4; ++n) {
            int kbase = kt * 64 + n * 16 + lg * 4;
#pragma unroll
            for (int r = 0; r < 4; ++r)
              if (kbase + r > qglob) accs[n][r] = -1e30f;
          }
        }

        // row max over 64 k: 16 in-lane values + 2 cross-lane rounds
        float pmax = fmaxf(fmaxf(fmaxf(accs[0][0], accs[0][1]), fmaxf(accs[0][2], accs[0][3])),
                           fmaxf(fmaxf(accs[1][0], accs[1][1]), fmaxf(accs[1][2], accs[1][3])));
        pmax = fmaxf(pmax,
               fmaxf(fmaxf(fmaxf(accs[2][0], accs[2][1]), fmaxf(accs[2][2], accs[2][3])),
                     fmaxf(fmaxf(accs[3][0], accs[3][1]), fmaxf(accs[3][2], accs[3][3]))));
        pmax = fmaxf(pmax, __shfl_xor(pmax, 16, 64));
        pmax = fmaxf(pmax, __shfl_xor(pmax, 32, 64));

        // defer-max: rescale only when some row's max grew by > 8 (log2 units)
        bool ok = (pmax <= mrun + 8.f);
        if (!__all(ok)) {
          float mnew = fmaxf(mrun, pmax);
          float alpha = exp2f(mrun - mnew);
          mrun = mnew;
          float alr[4];
#pragma unroll
          for (int r = 0; r < 4; ++r)
            alr[r] = __shfl(alpha, lg * 4 + r, 64);
#pragma unroll
          for (int r = 0; r < 4; ++r) accl[r] *= alr[r];
#pragma unroll
          for (int n2 = 0; n2 < 8; ++n2)
#pragma unroll
            for (int r = 0; r < 4; ++r) acco[n2][r] *= alr[r];
        }

        // P = exp2(S - m); pack to bf16 dwords: w0[n]={r0,r1}, w1[n]={r2,r3}
        uint32_t w0[4], w1[4];
#pragma unroll
        for (int n = 0; n < 4; ++n) {
          float p0 = exp2f(accs[n][0] - mrun);
          float p1 = exp2f(accs[n][1] - mrun);
          float p2 = exp2f(accs[n][2] - mrun);
          float p3 = exp2f(accs[n][3] - mrun);
          w0[n] = cvt_pk_bf16(p0, p1);
          w1[n] = cvt_pk_bf16(p2, p3);
        }

        // Redistribute P to PV A-fragment layout (in-register crossbar)
        const int s1 = ((lg & 1) << 5) | lr;
        const int s2 = s1 + 16;
        uint32_t F[4][4];
#pragma unroll
        for (int n = 0; n < 4; ++n) {
          F[n][0] = __shfl((int)w0[n], s1, 64);
          F[n][1] = __shfl((int)w1[n], s1, 64);
          F[n][2] = __shfl((int)w0[n], s2, 64);
          F[n][3] = __shfl((int)w1[n], s2, 64);
        }
        const bool hi = (lg & 2);
        bf16x8 pa[2];
#pragma unroll
        for (int ks = 0; ks < 2; ++ks) {
          union { uint32_t d[4]; bf16x8 v; } u;
#pragma unroll
          for (int j = 0; j < 4; ++j)
            u.d[j] = hi ? F[ks * 2 + 1][j] : F[ks * 2][j];
          pa[ks] = u.v;
        }

        // PV: out[16 q][128 d] += P[16 q][64 k] * V[64 k][128 d]; l += P*ones
        __builtin_amdgcn_s_setprio(1);
#pragma unroll
        for (int ks = 0; ks < 2; ++ks) {
          int cb = (ks * 32 + lg * 8) * 2;
#pragma unroll
          for (int n2 = 0; n2 < 8; ++n2) {
            int d = n2 * 16 + lr;
            bf16x8 bv = *(const bf16x8*)(Vc + d * 128 + (cb ^ ((d & 7) << 4)));
            acco[n2] = __builtin_amdgcn_mfma_f32_16x16x32_bf16(pa[ks], bv, acco[n2], 0, 0, 0);
          }
          accl = __builtin_amdgcn_mfma_f32_16x16x32_bf16(pa[ks], ones, accl, 0, 0, 0);
        }
        __builtin_amdgcn_s_setprio(0);
      }
      MEMFENCE;
      cur = nxt;
    }

    // epilogue: attn_out[b][s][h][d] (bf16)
#pragma unroll
    for (int n2 = 0; n2 < 8; ++n2) {
      int d = n2 * 16 + lr;
#pragma unroll
      for (int r = 0; r < 4; ++r) {
        int q = qrow0 + r;
        Ob[((size_t)b * NS + q) * ND + h * HDIM + d] = f2bf(acco[n2][r] / accl[r]);
      }
    }
  }
}

extern "C" void kernel_launch(void* const* d_in, const int* in_sizes, int n_in,
                              void* d_out, int out_size, void* d_ws, size_t ws_size,
                              hipStream_t stream) {
  const float* x = (const float*)d_in[0];
  const float* fc = (const float*)d_in[1];
  const float* wqkv = (const float*)d_in[2];
  const float* wo = (const float*)d_in[3];
  float* out = (float*)d_out;
  char* ws = (char*)d_ws;
  size_t off = 0;
  u16* xb = (u16*)(ws + off);    off += (size_t)TOK * ND * 2;
  u16* wqkvb = (u16*)(ws + off); off += (size_t)QKVD * ND * 2;
  u16* wob = (u16*)(ws + off);   off += (size_t)ND * ND * 2;
  u16* Qb = (u16*)(ws + off);    off += (size_t)NB * NH * NS * HDIM * 2;
  u16* Kb = (u16*)(ws + off);    off += (size_t)NB * NKVH * NS * HDIM * 2;
  u16* Vtb = (u16*)(ws + off);   off += (size_t)NB * NKVH * NS * HDIM * 2;
  u16* attnb = (u16*)(ws + off); off += (size_t)TOK * ND * 2;
  (void)ws_size; (void)in_sizes; (void)n_in; (void)out_size;

  constexpr int CVTN = (TOK * ND + QKVD * ND + ND * ND) / 4;
  cvt3<<<CVTN / 256, 256, 0, stream>>>(x, wqkv, wo, xb, wqkvb, wob);
  gemm_bt<2><<<dim3(QKVD / 128, TOK / 128), 256, 0, stream>>>(
      xb, wqkvb, nullptr, TOK, QKVD, ND, fc, Qb, Kb, Vtb);
  flash_attn<<<dim3(256), 512, 0, stream>>>(Qb, Kb, Vtb, attnb);
  gemm_bt<0><<<dim3(ND / 128, TOK / 128), 256, 0, stream>>>(
      attnb, wob, out, TOK, ND, ND, nullptr, nullptr, nullptr, nullptr);
}